// Round 2
// baseline (32855.490 us; speedup 1.0000x reference)
//
#include <hip/hip_runtime.h>
#include <hip/hip_bf16.h>
#include <math.h>

#define TB 256   // batch
#define TD 131   // input/output feature dim
#define TH 256   // hidden
#define NG 32    // persistent workgroups
#define BG 8     // batch rows per WG
#define K0  387  // layer0 true K (131 + 256)
#define K0P 416  // layer0 padded K (13 * 32)
#define KT0 13
#define K1  512  // layer1 K (256 + 256)
#define KT1 16
#define A0S 440  // A0 LDS row stride (bf16 elems) — 2-way-bank-safe, 16B aligned
#define A1S 520  // A1 LDS row stride
#define ZS  1026 // z LDS row stride (f32)

// ws element offsets (bf16 units) for packed weights
#define OFF_W0E 0
#define OFF_W1E (1024 * K0P)
#define OFF_W0D (OFF_W1E + 1024 * K1)
#define OFF_W1D (OFF_W0D + 1024 * K0P)
#define OFF_END (OFF_W1D + 1024 * K1)

typedef __attribute__((ext_vector_type(8))) short short8;
typedef __attribute__((ext_vector_type(4))) float f32x4;

// ---- weight packing: W0cat[n][k] = [Wih0(131) | Whh0(256) | 0-pad]
__global__ __launch_bounds__(256) void pack_w0(const float* __restrict__ Wih,
                                               const float* __restrict__ Whh,
                                               __hip_bfloat16* __restrict__ dst) {
    int idx = blockIdx.x * 256 + threadIdx.x;
    if (idx >= 1024 * K0P) return;
    int n = idx / K0P, k = idx - n * K0P;
    float v = 0.f;
    if (k < TD) v = Wih[n * TD + k];
    else if (k < K0) v = Whh[n * TH + (k - TD)];
    dst[idx] = __float2bfloat16(v);
}

// W1cat[n][k] = [Wih1(256) | Whh1(256)]
__global__ __launch_bounds__(256) void pack_w1(const float* __restrict__ Wih,
                                               const float* __restrict__ Whh,
                                               __hip_bfloat16* __restrict__ dst) {
    int idx = blockIdx.x * 256 + threadIdx.x;
    if (idx >= 1024 * K1) return;
    int n = idx / K1, k = idx - n * K1;
    float v = (k < TH) ? Wih[n * TH + k] : Whh[n * TH + (k - TH)];
    dst[idx] = __float2bfloat16(v);
}

__global__ __launch_bounds__(256) void pack_bias(const float* __restrict__ bih,
                                                 const float* __restrict__ bhh,
                                                 float* __restrict__ dst) {
    int idx = blockIdx.x * 256 + threadIdx.x;
    if (idx < 1024) dst[idx] = bih[idx] + bhh[idx];
}

// ---- persistent LSTM: 32 WGs x 512 threads; WG g owns batch rows [g*8, g*8+8)
// for the entire enc+dec recurrence. All state in LDS. Weights streamed from
// L2 as bf16 MFMA B-fragments. z (8x1024 fp32) round-trips through LDS so each
// thread can fuse all 4 gates of its (b,j).
__global__ __launch_bounds__(512) void lstm_persistent(
    const float* __restrict__ X, const float* __restrict__ Y,
    const __hip_bfloat16* __restrict__ wts, const float* __restrict__ bsum,
    __hip_bfloat16* __restrict__ h1_all) {
    __shared__ __align__(16) __hip_bfloat16 A0[16 * A0S];  // [x(131)|h0(256)|0pad]
    __shared__ __align__(16) __hip_bfloat16 A1[16 * A1S];  // [h0_new(256)|h1(256)|pad]
    __shared__ __align__(16) float zb[16 * ZS];
    __shared__ float c0[BG * TH], c1[BG * TH];

    const int tid  = threadIdx.x;
    const int g    = blockIdx.x;
    const int lane = tid & 63;
    const int wv   = tid >> 6;           // wave 0..7
    const int lrow = lane & 15;          // frag row (A) / col (B,D)
    const int lk8  = (lane >> 4) * 8;    // frag k-offset
    const int crow = (lane >> 4) * 4;    // D-frag row base

    for (int i = tid; i < 16 * A0S; i += 512) A0[i] = __float2bfloat16(0.f);
    for (int i = tid; i < 16 * A1S; i += 512) A1[i] = __float2bfloat16(0.f);
    for (int i = tid; i < BG * TH; i += 512) { c0[i] = 0.f; c1[i] = 0.f; }
    __syncthreads();

    for (int phase = 0; phase < 2; ++phase) {
        const __hip_bfloat16* W0 = wts + (phase ? OFF_W0D : OFF_W0E);
        const __hip_bfloat16* W1 = wts + (phase ? OFF_W1D : OFF_W1E);
        const float* b0 = bsum + phase * 2048;
        const float* b1 = b0 + 1024;

        for (int t = 0; t < 256; ++t) {
            const float* xsrc = (phase == 0)
                ? X + (size_t)t * TB * TD
                : ((t == 0) ? X + (size_t)256 * TB * TD : Y + (size_t)(t - 1) * TB * TD);

            // stage x tile (8 x 131, fp32 -> bf16)
            for (int e = tid; e < BG * TD; e += 512) {
                int r = e / TD, k = e - r * TD;
                A0[r * A0S + k] = __float2bfloat16(xsrc[(size_t)(g * BG + r) * TD + k]);
            }
            __syncthreads();

            // ---- layer 0: z = A0 @ W0^T  (M=16(8 used), N=1024, K=416)
            {
                f32x4 acc[8];
                #pragma unroll
                for (int i = 0; i < 8; ++i) acc[i] = (f32x4){0.f, 0.f, 0.f, 0.f};
                #pragma unroll
                for (int kt = 0; kt < KT0; ++kt) {
                    short8 a = *reinterpret_cast<const short8*>(&A0[lrow * A0S + kt * 32 + lk8]);
                    #pragma unroll
                    for (int i = 0; i < 8; ++i) {
                        int n = (wv * 8 + i) * 16 + lrow;
                        short8 w = *reinterpret_cast<const short8*>(&W0[(size_t)n * K0P + kt * 32 + lk8]);
                        acc[i] = __builtin_amdgcn_mfma_f32_16x16x32_bf16(a, w, acc[i], 0, 0, 0);
                    }
                }
                #pragma unroll
                for (int i = 0; i < 8; ++i) {
                    int ct = (wv * 8 + i) * 16 + lrow;
                    #pragma unroll
                    for (int r = 0; r < 4; ++r) zb[(crow + r) * ZS + ct] = acc[i][r];
                }
            }
            __syncthreads();

            // gates layer 0 -> h0 into A0 (recurrent) and A1 (layer-1 input)
            for (int e = tid; e < BG * TH; e += 512) {
                int b = e >> 8, j = e & 255;
                float zi = zb[b * ZS + j]       + b0[j];
                float zf = zb[b * ZS + 256 + j] + b0[256 + j];
                float zg = zb[b * ZS + 512 + j] + b0[512 + j];
                float zo = zb[b * ZS + 768 + j] + b0[768 + j];
                float ig = 1.f / (1.f + expf(-zi));
                float fg = 1.f / (1.f + expf(-zf));
                float og = 1.f / (1.f + expf(-zo));
                float cnew = fg * c0[e] + ig * tanhf(zg);
                c0[e] = cnew;
                __hip_bfloat16 hb = __float2bfloat16(og * tanhf(cnew));
                A0[b * A0S + TD + j] = hb;
                A1[b * A1S + j] = hb;
            }
            __syncthreads();

            // ---- layer 1: z = A1 @ W1^T  (K=512)
            {
                f32x4 acc[8];
                #pragma unroll
                for (int i = 0; i < 8; ++i) acc[i] = (f32x4){0.f, 0.f, 0.f, 0.f};
                #pragma unroll
                for (int kt = 0; kt < KT1; ++kt) {
                    short8 a = *reinterpret_cast<const short8*>(&A1[lrow * A1S + kt * 32 + lk8]);
                    #pragma unroll
                    for (int i = 0; i < 8; ++i) {
                        int n = (wv * 8 + i) * 16 + lrow;
                        short8 w = *reinterpret_cast<const short8*>(&W1[(size_t)n * K1 + kt * 32 + lk8]);
                        acc[i] = __builtin_amdgcn_mfma_f32_16x16x32_bf16(a, w, acc[i], 0, 0, 0);
                    }
                }
                #pragma unroll
                for (int i = 0; i < 8; ++i) {
                    int ct = (wv * 8 + i) * 16 + lrow;
                    #pragma unroll
                    for (int r = 0; r < 4; ++r) zb[(crow + r) * ZS + ct] = acc[i][r];
                }
            }
            __syncthreads();

            // gates layer 1 -> h1 into A1 (recurrent); decoder: dump to h1_all
            for (int e = tid; e < BG * TH; e += 512) {
                int b = e >> 8, j = e & 255;
                float zi = zb[b * ZS + j]       + b1[j];
                float zf = zb[b * ZS + 256 + j] + b1[256 + j];
                float zg = zb[b * ZS + 512 + j] + b1[512 + j];
                float zo = zb[b * ZS + 768 + j] + b1[768 + j];
                float ig = 1.f / (1.f + expf(-zi));
                float fg = 1.f / (1.f + expf(-zf));
                float og = 1.f / (1.f + expf(-zo));
                float cnew = fg * c1[e] + ig * tanhf(zg);
                c1[e] = cnew;
                __hip_bfloat16 hb = __float2bfloat16(og * tanhf(cnew));
                A1[b * A1S + TH + j] = hb;
                if (phase == 1)
                    h1_all[((size_t)t * TB + g * BG + b) * TH + j] = hb;
            }
            __syncthreads();
        }
    }
}

// ---- batched emit: one block per (t,b) row; logits + log_softmax over 131
__global__ __launch_bounds__(256) void emit_kernel(
    const __hip_bfloat16* __restrict__ h1,
    const float* __restrict__ linW,
    const float* __restrict__ linb,
    float* __restrict__ out) {
    __shared__ float sh[TH];
    __shared__ float red[256];
    const size_t row = blockIdx.x;
    const int tid = threadIdx.x;
    sh[tid] = __bfloat162float(h1[row * TH + tid]);
    __syncthreads();

    float logit = 0.f;
    if (tid < TD) {
        const float* w = &linW[(size_t)tid * TH];
        float acc = 0.f;
        #pragma unroll 4
        for (int k = 0; k < TH; k += 4) {
            float4 wv = *reinterpret_cast<const float4*>(&w[k]);
            acc = fmaf(sh[k + 0], wv.x, acc);
            acc = fmaf(sh[k + 1], wv.y, acc);
            acc = fmaf(sh[k + 2], wv.z, acc);
            acc = fmaf(sh[k + 3], wv.w, acc);
        }
        logit = acc + linb[tid];
    }

    red[tid] = (tid < TD) ? logit : -INFINITY;
    __syncthreads();
    for (int s = 128; s > 0; s >>= 1) {
        if (tid < s) red[tid] = fmaxf(red[tid], red[tid + s]);
        __syncthreads();
    }
    float m = red[0];
    __syncthreads();
    red[tid] = (tid < TD) ? expf(logit - m) : 0.f;
    __syncthreads();
    for (int s = 128; s > 0; s >>= 1) {
        if (tid < s) red[tid] += red[tid + s];
        __syncthreads();
    }
    float lse = m + logf(red[0]);
    if (tid < TD) out[row * TD + tid] = logit - lse;
}

extern "C" void kernel_launch(void* const* d_in, const int* in_sizes, int n_in,
                              void* d_out, int out_size, void* d_ws, size_t ws_size,
                              hipStream_t stream) {
    const float* X     = (const float*)d_in[0];
    const float* Y     = (const float*)d_in[1];
    const float* eWih0 = (const float*)d_in[2];
    const float* eWhh0 = (const float*)d_in[3];
    const float* ebih0 = (const float*)d_in[4];
    const float* ebhh0 = (const float*)d_in[5];
    const float* eWih1 = (const float*)d_in[6];
    const float* eWhh1 = (const float*)d_in[7];
    const float* ebih1 = (const float*)d_in[8];
    const float* ebhh1 = (const float*)d_in[9];
    const float* dWih0 = (const float*)d_in[10];
    const float* dWhh0 = (const float*)d_in[11];
    const float* dbih0 = (const float*)d_in[12];
    const float* dbhh0 = (const float*)d_in[13];
    const float* dWih1 = (const float*)d_in[14];
    const float* dWhh1 = (const float*)d_in[15];
    const float* dbih1 = (const float*)d_in[16];
    const float* dbhh1 = (const float*)d_in[17];
    const float* linW  = (const float*)d_in[18];
    const float* linb  = (const float*)d_in[19];
    float* out = (float*)d_out;

    // ws layout: packed bf16 weights | 4x1024 f32 biases | h1_all bf16
    __hip_bfloat16* wts = (__hip_bfloat16*)d_ws;
    float* bsum = (float*)(wts + OFF_END);
    __hip_bfloat16* h1_all = (__hip_bfloat16*)(bsum + 4096);

    pack_w0<<<dim3((1024 * K0P + 255) / 256), dim3(256), 0, stream>>>(eWih0, eWhh0, wts + OFF_W0E);
    pack_w1<<<dim3((1024 * K1 + 255) / 256), dim3(256), 0, stream>>>(eWih1, eWhh1, wts + OFF_W1E);
    pack_w0<<<dim3((1024 * K0P + 255) / 256), dim3(256), 0, stream>>>(dWih0, dWhh0, wts + OFF_W0D);
    pack_w1<<<dim3((1024 * K1 + 255) / 256), dim3(256), 0, stream>>>(dWih1, dWhh1, wts + OFF_W1D);
    pack_bias<<<dim3(4), dim3(256), 0, stream>>>(ebih0, ebhh0, bsum + 0);
    pack_bias<<<dim3(4), dim3(256), 0, stream>>>(ebih1, ebhh1, bsum + 1024);
    pack_bias<<<dim3(4), dim3(256), 0, stream>>>(dbih0, dbhh0, bsum + 2048);
    pack_bias<<<dim3(4), dim3(256), 0, stream>>>(dbih1, dbhh1, bsum + 3072);

    lstm_persistent<<<dim3(NG), dim3(512), 0, stream>>>(X, Y, wts, bsum, h1_all);

    emit_kernel<<<dim3(256 * TB), dim3(256), 0, stream>>>(h1_all, linW, linb, out);
}

// Round 3
// 9869.193 us; speedup vs baseline: 3.3291x; 3.3291x over previous
//
#include <hip/hip_runtime.h>
#include <hip/hip_bf16.h>
#include <math.h>

typedef __attribute__((ext_vector_type(8))) short short8;
typedef __attribute__((ext_vector_type(4))) float f32x4;

#define STEPS 512
#define BB 256      // batch
#define HH 256      // hidden
#define DD 131      // feature dim
#define XP 160      // x part padded to 5*32
#define K0P 416     // layer0 K: 160 + 256
#define KS0 424     // LDS row stride (bank-safe, 16B aligned)
#define K1  512     // layer1 K: 256 + 256
#define KS1 520
#define RING 8
#define HN (BB * HH)   // 65536 elems per ring slot

// ws element offsets (bf16 units)
#define OFF_W0E 0
#define OFF_W0D (OFF_W0E + 1024 * K0P)
#define OFF_W1E (OFF_W0D + 1024 * K0P)
#define OFF_W1D (OFF_W1E + 1024 * K1)
#define OFF_LW  (OFF_W1D + 1024 * K1)
#define OFF_XBF (OFF_LW + 160 * 256)
#define OFF_H0R (OFF_XBF + STEPS * BB * XP)
#define OFF_H1R (OFF_H0R + RING * HN)
#define OFF_H1A (OFF_H1R + RING * HN)
#define OFF_BF16_END (OFF_H1A + 256 * HN)

__device__ __forceinline__ float rcp_(float x) { return __builtin_amdgcn_rcpf(x); }
__device__ __forceinline__ float fsigm(float x) { return rcp_(1.f + __expf(-x)); }
__device__ __forceinline__ float ftanh(float x) {
    float t = __expf(-2.f * fabsf(x));
    float r = (1.f - t) * rcp_(1.f + t);
    return copysignf(r, x);
}

// ---------------- packing kernels ----------------
// W0 packed: pcol p = ct*128 + g*32 + jc  (h-col j = ct*32+jc), K = [x:131|pad|h:256]
__global__ __launch_bounds__(256) void pack_w0(const float* __restrict__ Wih,
                                               const float* __restrict__ Whh,
                                               __hip_bfloat16* __restrict__ dst) {
    int idx = blockIdx.x * 256 + threadIdx.x;   // 1024*416
    int p = idx / K0P, k = idx - p * K0P;
    int ct = p >> 7, rem = p & 127, g = rem >> 5, jc = rem & 31;
    int orow = g * 256 + ct * 32 + jc;
    float v = 0.f;
    if (k < DD) v = Wih[orow * DD + k];
    else if (k >= XP) v = Whh[orow * HH + (k - XP)];
    dst[idx] = __float2bfloat16(v);
}

__global__ __launch_bounds__(256) void pack_w1(const float* __restrict__ Wih,
                                               const float* __restrict__ Whh,
                                               __hip_bfloat16* __restrict__ dst) {
    int idx = blockIdx.x * 256 + threadIdx.x;   // 1024*512
    int p = idx >> 9, k = idx & 511;
    int ct = p >> 7, rem = p & 127, g = rem >> 5, jc = rem & 31;
    int orow = g * 256 + ct * 32 + jc;
    float v = (k < HH) ? Wih[orow * HH + k] : Whh[orow * HH + (k - HH)];
    dst[idx] = __float2bfloat16(v);
}

__global__ __launch_bounds__(256) void pack_bias(const float* __restrict__ bih,
                                                 const float* __restrict__ bhh,
                                                 float* __restrict__ dst) {
    int idx = blockIdx.x * 256 + threadIdx.x;
    if (idx < 1024) dst[idx] = bih[idx] + bhh[idx];
}

// Xbf[s][b][kp], kp in [0,160): s<256 -> X[s]; s==256 -> X[256]; else Y[s-257]
__global__ __launch_bounds__(256) void pack_xbf(const float* __restrict__ X,
                                                const float* __restrict__ Y,
                                                __hip_bfloat16* __restrict__ dst) {
    int idx = blockIdx.x * 256 + threadIdx.x;   // 512*256*160
    int kp = idx % XP;
    int rb = idx / XP;
    int b = rb & 255, s = rb >> 8;
    const float* src;
    if (s <= 256) src = X + ((size_t)s * BB + b) * DD;
    else          src = Y + ((size_t)(s - 257) * BB + b) * DD;
    dst[idx] = __float2bfloat16(kp < DD ? src[kp] : 0.f);
}

__global__ __launch_bounds__(256) void pack_linw(const float* __restrict__ linW,
                                                 __hip_bfloat16* __restrict__ dst) {
    int idx = blockIdx.x * 256 + threadIdx.x;   // 160*256
    int j = idx >> 8, k = idx & 255;
    dst[idx] = __float2bfloat16(j < DD ? linW[j * HH + k] : 0.f);
}

__global__ __launch_bounds__(256) void pack_linb(const float* __restrict__ linb,
                                                 float* __restrict__ dst) {
    int idx = threadIdx.x;
    if (idx < 160) dst[idx] = (idx < DD) ? linb[idx] : -1.0e30f;
}

__global__ __launch_bounds__(256) void init_sync(__hip_bfloat16* __restrict__ h0ring,
                                                 __hip_bfloat16* __restrict__ h1ring,
                                                 int* __restrict__ flags) {
    int idx = blockIdx.x * 256 + threadIdx.x;
    if (idx < HN) {
        h0ring[(size_t)(RING - 1) * HN + idx] = __float2bfloat16(0.f);
        h1ring[(size_t)(RING - 1) * HN + idx] = __float2bfloat16(0.f);
    }
    if (idx < 64) flags[idx * 16] = 0;
}

// ---------------- persistent pipelined LSTM ----------------
// 64 WGs x 512 threads. wg = [layer(2)][bt(4)][ct(8)].
// Each WG: weights slice in LDS, c-state in VGPRs, h via global ring + flags.
__global__ __launch_bounds__(512) void lstm_persistent(
    const __hip_bfloat16* __restrict__ wsb,
    const float* __restrict__ bsum,
    int* __restrict__ flags,
    __hip_bfloat16* __restrict__ h0ring,
    __hip_bfloat16* __restrict__ h1ring,
    __hip_bfloat16* __restrict__ h1all) {
    extern __shared__ __align__(16) __hip_bfloat16 Wlds[];
    const int tid = threadIdx.x;
    const int wg = blockIdx.x;
    const int layer = wg >> 5;
    const int bt = (wg >> 3) & 3;
    const int ct = wg & 7;
    const int lane = tid & 63;
    const int wv = tid >> 6;
    const int mt = wv & 3;        // M-tile (16 rows)
    const int nh = wv >> 2;       // jc half (16 cols)
    const int lrow = lane & 15;
    const int lk8 = (lane >> 4) * 8;
    const int crow = (lane >> 4) * 4;

    const int K = layer ? K1 : K0P;
    const int arow = bt * 64 + mt * 16 + lrow;
    const int jcol = ct * 32 + nh * 16 + lrow;
    const __hip_bfloat16* Xbf = wsb + OFF_XBF;

    f32x4 creg = {0.f, 0.f, 0.f, 0.f};
    float br[4];
    int phase = -1;

    for (int s = 0; s < STEPS; ++s) {
        int ph = s >> 8;
        if (ph != phase) {
            phase = ph;
            const __hip_bfloat16* wsrc = wsb +
                (layer ? (phase ? OFF_W1D : OFF_W1E) : (phase ? OFF_W0D : OFF_W0E)) +
                (size_t)ct * 128 * K;
            const int KS = layer ? KS1 : KS0;
            const int KC = K >> 3;
            for (int e = tid; e < 128 * KC; e += 512) {
                int p = e / KC, kc = e - p * KC;
                *reinterpret_cast<short8*>(&Wlds[p * KS + kc * 8]) =
                    *reinterpret_cast<const short8*>(&wsrc[(size_t)p * K + kc * 8]);
            }
            #pragma unroll
            for (int g = 0; g < 4; ++g)
                br[g] = bsum[phase * 2048 + layer * 1024 + g * 256 + jcol];
            __syncthreads();
        }

        // ---- spin-wait on producer flags (+ ring backpressure)
        {
            const int tgt0 = layer ? s + 1 : s;          // need h0[s] / h0[s-1]
            const int tgt1 = layer ? s : s - (RING - 1); // need h1[s-1] / BP
            if (tid < 16) {
                int tg = (tid < 8) ? tgt0 : tgt1;
                if (tg > 0) {
                    int* fp = flags + (((tid < 8) ? 0 : 32) + bt * 8 + (tid & 7)) * 16;
                    while (__hip_atomic_load(fp, __ATOMIC_ACQUIRE,
                                             __HIP_MEMORY_SCOPE_AGENT) < tg)
                        __builtin_amdgcn_s_sleep(1);
                }
            }
            __syncthreads();
        }

        // ---- GEMM: acc[g] = A @ W^T slice (gate g), f32 accum
        f32x4 acc[4];
        #pragma unroll
        for (int g = 0; g < 4; ++g) acc[g] = (f32x4){0.f, 0.f, 0.f, 0.f};

        if (layer == 0) {
            const short8* xr8 = reinterpret_cast<const short8*>(
                &Xbf[((size_t)s * BB + arow) * XP]);
            const __hip_bfloat16* hb =
                &h0ring[(size_t)((s + RING - 1) & (RING - 1)) * HN + (size_t)arow * HH];
            #pragma unroll
            for (int kt = 0; kt < 13; ++kt) {
                short8 a;
                if (kt < 5) a = xr8[kt * 4 + (lk8 >> 3)];
                else a = *reinterpret_cast<const short8*>(&hb[(kt - 5) * 32 + lk8]);
                #pragma unroll
                for (int g = 0; g < 4; ++g) {
                    short8 w = *reinterpret_cast<const short8*>(
                        &Wlds[(g * 32 + nh * 16 + lrow) * KS0 + kt * 32 + lk8]);
                    acc[g] = __builtin_amdgcn_mfma_f32_16x16x32_bf16(a, w, acc[g], 0, 0, 0);
                }
            }
        } else {
            const __hip_bfloat16* h0b =
                &h0ring[(size_t)(s & (RING - 1)) * HN + (size_t)arow * HH];
            const __hip_bfloat16* h1b =
                &h1ring[(size_t)((s + RING - 1) & (RING - 1)) * HN + (size_t)arow * HH];
            #pragma unroll
            for (int kt = 0; kt < 16; ++kt) {
                short8 a;
                if (kt < 8) a = *reinterpret_cast<const short8*>(&h0b[kt * 32 + lk8]);
                else a = *reinterpret_cast<const short8*>(&h1b[(kt - 8) * 32 + lk8]);
                #pragma unroll
                for (int g = 0; g < 4; ++g) {
                    short8 w = *reinterpret_cast<const short8*>(
                        &Wlds[(g * 32 + nh * 16 + lrow) * KS1 + kt * 32 + lk8]);
                    acc[g] = __builtin_amdgcn_mfma_f32_16x16x32_bf16(a, w, acc[g], 0, 0, 0);
                }
            }
        }

        // ---- gates + h store (all 4 gates of (b,jcol) live in this lane)
        __hip_bfloat16* rbase =
            (layer ? h1ring : h0ring) + (size_t)(s & (RING - 1)) * HN;
        #pragma unroll
        for (int r = 0; r < 4; ++r) {
            float zi = acc[0][r] + br[0];
            float zf = acc[1][r] + br[1];
            float zg = acc[2][r] + br[2];
            float zo = acc[3][r] + br[3];
            float ig = fsigm(zi), fg = fsigm(zf), og = fsigm(zo);
            float cn = fg * creg[r] + ig * ftanh(zg);
            creg[r] = cn;
            __hip_bfloat16 hb = __float2bfloat16(og * ftanh(cn));
            int brow = bt * 64 + mt * 16 + crow + r;
            rbase[(size_t)brow * HH + jcol] = hb;
            if (layer == 1 && s >= 256)
                h1all[((size_t)(s - 256) * BB + brow) * HH + jcol] = hb;
        }

        // ---- release
        __threadfence();
        __syncthreads();
        if (tid == 0)
            __hip_atomic_store(flags + (layer * 32 + bt * 8 + ct) * 16, s + 1,
                               __ATOMIC_RELEASE, __HIP_MEMORY_SCOPE_AGENT);
    }
}

// ---------------- MFMA emit: logits + log_softmax ----------------
// 1024 blocks x 256 thr; block handles 64 rows of (t*B+b), N=160 (131 valid)
__global__ __launch_bounds__(256) void emit_mfma(
    const __hip_bfloat16* __restrict__ h1all,
    const __hip_bfloat16* __restrict__ lW,
    const float* __restrict__ lb,
    float* __restrict__ out) {
    __shared__ float lbs[160];
    const int tid = threadIdx.x;
    const int wv = tid >> 6, lane = tid & 63;
    const int lrow = lane & 15, lk8 = (lane >> 4) * 8, crow = (lane >> 4) * 4;
    const int row0 = blockIdx.x * 64;
    if (tid < 160) lbs[tid] = lb[tid];
    __syncthreads();

    f32x4 acc[10];
    #pragma unroll
    for (int f = 0; f < 10; ++f) acc[f] = (f32x4){0.f, 0.f, 0.f, 0.f};
    const int arow = row0 + wv * 16 + lrow;
    #pragma unroll
    for (int kt = 0; kt < 8; ++kt) {
        short8 a = *reinterpret_cast<const short8*>(
            &h1all[(size_t)arow * HH + kt * 32 + lk8]);
        #pragma unroll
        for (int f = 0; f < 10; ++f) {
            short8 w = *reinterpret_cast<const short8*>(
                &lW[(size_t)(f * 16 + lrow) * HH + kt * 32 + lk8]);
            acc[f] = __builtin_amdgcn_mfma_f32_16x16x32_bf16(a, w, acc[f], 0, 0, 0);
        }
    }
    #pragma unroll
    for (int r = 0; r < 4; ++r) {
        float m = -3.0e38f;
        #pragma unroll
        for (int f = 0; f < 10; ++f) m = fmaxf(m, acc[f][r] + lbs[f * 16 + lrow]);
        #pragma unroll
        for (int d = 1; d < 16; d <<= 1) m = fmaxf(m, __shfl_xor(m, d, 64));
        float ss = 0.f;
        #pragma unroll
        for (int f = 0; f < 10; ++f) ss += __expf(acc[f][r] + lbs[f * 16 + lrow] - m);
        #pragma unroll
        for (int d = 1; d < 16; d <<= 1) ss += __shfl_xor(ss, d, 64);
        float lse = m + logf(ss);
        int grow = row0 + wv * 16 + crow + r;
        #pragma unroll
        for (int f = 0; f < 9; ++f) {
            int j = f * 16 + lrow;
            if (j < DD)
                out[(size_t)grow * DD + j] = acc[f][r] + lbs[j] - lse;
        }
    }
}

extern "C" void kernel_launch(void* const* d_in, const int* in_sizes, int n_in,
                              void* d_out, int out_size, void* d_ws, size_t ws_size,
                              hipStream_t stream) {
    const float* X     = (const float*)d_in[0];
    const float* Y     = (const float*)d_in[1];
    const float* eWih0 = (const float*)d_in[2];
    const float* eWhh0 = (const float*)d_in[3];
    const float* ebih0 = (const float*)d_in[4];
    const float* ebhh0 = (const float*)d_in[5];
    const float* eWih1 = (const float*)d_in[6];
    const float* eWhh1 = (const float*)d_in[7];
    const float* ebih1 = (const float*)d_in[8];
    const float* ebhh1 = (const float*)d_in[9];
    const float* dWih0 = (const float*)d_in[10];
    const float* dWhh0 = (const float*)d_in[11];
    const float* dbih0 = (const float*)d_in[12];
    const float* dbhh0 = (const float*)d_in[13];
    const float* dWih1 = (const float*)d_in[14];
    const float* dWhh1 = (const float*)d_in[15];
    const float* dbih1 = (const float*)d_in[16];
    const float* dbhh1 = (const float*)d_in[17];
    const float* linW  = (const float*)d_in[18];
    const float* linb  = (const float*)d_in[19];
    float* out = (float*)d_out;

    __hip_bfloat16* wsb = (__hip_bfloat16*)d_ws;
    float* freg  = (float*)(wsb + OFF_BF16_END);
    float* bsum  = freg;          // 4096 f32
    float* linbp = freg + 4096;   // 160 (+pad)
    int*   flags = (int*)(freg + 4096 + 192);  // 64 x 16-int stride

    pack_w0<<<dim3(1664), dim3(256), 0, stream>>>(eWih0, eWhh0, wsb + OFF_W0E);
    pack_w0<<<dim3(1664), dim3(256), 0, stream>>>(dWih0, dWhh0, wsb + OFF_W0D);
    pack_w1<<<dim3(2048), dim3(256), 0, stream>>>(eWih1, eWhh1, wsb + OFF_W1E);
    pack_w1<<<dim3(2048), dim3(256), 0, stream>>>(dWih1, dWhh1, wsb + OFF_W1D);
    pack_bias<<<dim3(4), dim3(256), 0, stream>>>(ebih0, ebhh0, bsum + 0);
    pack_bias<<<dim3(4), dim3(256), 0, stream>>>(ebih1, ebhh1, bsum + 1024);
    pack_bias<<<dim3(4), dim3(256), 0, stream>>>(dbih0, dbhh0, bsum + 2048);
    pack_bias<<<dim3(4), dim3(256), 0, stream>>>(dbih1, dbhh1, bsum + 3072);
    pack_xbf<<<dim3(81920), dim3(256), 0, stream>>>(X, Y, wsb + OFF_XBF);
    pack_linw<<<dim3(160), dim3(256), 0, stream>>>(linW, wsb + OFF_LW);
    pack_linb<<<dim3(1), dim3(256), 0, stream>>>(linb, linbp);
    init_sync<<<dim3(256), dim3(256), 0, stream>>>(wsb + OFF_H0R, wsb + OFF_H1R, flags);

    hipFuncSetAttribute((const void*)lstm_persistent,
                        hipFuncAttributeMaxDynamicSharedMemorySize, 128 * KS1 * 2);
    lstm_persistent<<<dim3(64), dim3(512), 128 * KS1 * 2, stream>>>(
        wsb, bsum, flags, wsb + OFF_H0R, wsb + OFF_H1R, wsb + OFF_H1A);

    emit_mfma<<<dim3(1024), dim3(256), 0, stream>>>(wsb + OFF_H1A, wsb + OFF_LW,
                                                    linbp, out);
}

// Round 4
// 5495.576 us; speedup vs baseline: 5.9785x; 1.7958x over previous
//
#include <hip/hip_runtime.h>
#include <hip/hip_bf16.h>
#include <math.h>

typedef __attribute__((ext_vector_type(8))) short short8;
typedef __attribute__((ext_vector_type(4))) float f32x4;
typedef unsigned long long u64;

#define STEPS 512
#define BB 256      // batch
#define HH 256      // hidden
#define DD 131      // feature dim
#define XP 160      // x padded to 5*32
#define K0P 416     // layer0 K: 160 + 256
#define KS0 424     // LDS stride (16B aligned, ~2-way banks)
#define K1  512     // layer1 K
#define KS1 520
#define RING 4
#define NGRP 8      // batch groups (32 rows each)
#define ROWS 32
#define RGELEM (RING * ROWS * HH)   // 32768 elems per group ring

// ws bf16-elem offsets
#define OFF_W0E 0
#define OFF_W0D (OFF_W0E + 1024 * K0P)
#define OFF_W1E (OFF_W0D + 1024 * K0P)
#define OFF_W1D (OFF_W1E + 1024 * K1)
#define OFF_LW  (OFF_W1D + 1024 * K1)
#define OFF_XBF (OFF_LW + 160 * 256)
#define OFF_H0R (OFF_XBF + (size_t)STEPS * BB * XP)
#define OFF_H1R (OFF_H0R + (size_t)NGRP * RGELEM)
#define OFF_H1A (OFF_H1R + (size_t)NGRP * RGELEM)
#define OFF_BF16_END (OFF_H1A + (size_t)256 * BB * HH)

// dynamic LDS byte offsets
#define LDS_W_BYTES 133120            // 2 phases x 64 pcols x KS1 x 2B (worst)
#define LDS_Z_OFF   LDS_W_BYTES       // zbuf f32 [32][68] = 8704
#define LDS_H_OFF   (LDS_W_BYTES + 8704)   // hbuf bf16 [32][16] = 1024
#define LDS_TOTAL   (LDS_H_OFF + 1024)

__device__ __forceinline__ float rcp_(float x) { return __builtin_amdgcn_rcpf(x); }
__device__ __forceinline__ float fsigm(float x) { return rcp_(1.f + __expf(-x)); }
__device__ __forceinline__ float ftanh(float x) {
    float t = __expf(-2.f * fabsf(x));
    float r = (1.f - t) * rcp_(1.f + t);
    return copysignf(r, x);
}

// ---------------- packing ----------------
// W0 packed rows p = ct*64 + g*16 + j  -> orig row g*256 + ct*16 + j
// K layout: [x 0..131 | pad ..160 | h 160..416]
__global__ __launch_bounds__(256) void pack_w0(const float* __restrict__ Wih,
                                               const float* __restrict__ Whh,
                                               __hip_bfloat16* __restrict__ dst) {
    int idx = blockIdx.x * 256 + threadIdx.x;       // 1024*416
    int p = idx / K0P, k = idx - p * K0P;
    int ct = p >> 6, local = p & 63, g = local >> 4, j = local & 15;
    int orow = g * 256 + ct * 16 + j;
    float v = 0.f;
    if (k < DD) v = Wih[orow * DD + k];
    else if (k >= XP) v = Whh[orow * HH + (k - XP)];
    dst[idx] = __float2bfloat16(v);
}

__global__ __launch_bounds__(256) void pack_w1(const float* __restrict__ Wih,
                                               const float* __restrict__ Whh,
                                               __hip_bfloat16* __restrict__ dst) {
    int idx = blockIdx.x * 256 + threadIdx.x;       // 1024*512
    int p = idx >> 9, k = idx & 511;
    int ct = p >> 6, local = p & 63, g = local >> 4, j = local & 15;
    int orow = g * 256 + ct * 16 + j;
    float v = (k < HH) ? Wih[orow * HH + k] : Whh[orow * HH + (k - HH)];
    dst[idx] = __float2bfloat16(v);
}

__global__ __launch_bounds__(256) void pack_bias(const float* __restrict__ bih,
                                                 const float* __restrict__ bhh,
                                                 float* __restrict__ dst) {
    int idx = blockIdx.x * 256 + threadIdx.x;
    if (idx < 1024) dst[idx] = bih[idx] + bhh[idx];
}

__global__ __launch_bounds__(256) void pack_xbf(const float* __restrict__ X,
                                                const float* __restrict__ Y,
                                                __hip_bfloat16* __restrict__ dst) {
    int idx = blockIdx.x * 256 + threadIdx.x;       // 512*256*160
    int kp = idx % XP;
    int rb = idx / XP;
    int b = rb & 255, s = rb >> 8;
    const float* src;
    if (s <= 256) src = X + ((size_t)s * BB + b) * DD;
    else          src = Y + ((size_t)(s - 257) * BB + b) * DD;
    dst[idx] = __float2bfloat16(kp < DD ? src[kp] : 0.f);
}

__global__ __launch_bounds__(256) void pack_linw(const float* __restrict__ linW,
                                                 __hip_bfloat16* __restrict__ dst) {
    int idx = blockIdx.x * 256 + threadIdx.x;       // 160*256
    int j = idx >> 8, k = idx & 255;
    dst[idx] = __float2bfloat16(j < DD ? linW[j * HH + k] : 0.f);
}

__global__ __launch_bounds__(256) void pack_linb(const float* __restrict__ linb,
                                                 float* __restrict__ dst) {
    int idx = threadIdx.x;
    if (idx < 160) dst[idx] = (idx < DD) ? linb[idx] : -1.0e30f;
}

__global__ __launch_bounds__(256) void init_sync(__hip_bfloat16* __restrict__ rings,
                                                 int* __restrict__ flags) {
    int idx = blockIdx.x * 256 + threadIdx.x;
    if (idx < 131072) ((u64*)rings)[idx] = 0ull;    // both rings (1 MB)
    if (idx < 256) flags[idx] = 0;
}

// ---------------- persistent pipelined LSTM ----------------
// 256 WGs x 512 thr. wg = [group(8)][layer(2)][ct(16)].
// Group g owns batch rows [g*32, g*32+32). Per WG: 16 h-cols x 4 gates,
// weight slices (both phases) in LDS, c in VGPRs. All cross-WG traffic via
// RELAXED/AGENT 8B atomics (plain sc0 sc1 loads/stores -> no wbl2/inv).
__global__ __launch_bounds__(512, 1) void lstm_persistent(
    const __hip_bfloat16* __restrict__ wsb,
    const float* __restrict__ bsum,
    int* __restrict__ flags,
    __hip_bfloat16* __restrict__ h0ring,
    __hip_bfloat16* __restrict__ h1ring,
    __hip_bfloat16* __restrict__ h1all) {
    extern __shared__ __align__(16) char lds[];
    __hip_bfloat16* Wlds = (__hip_bfloat16*)lds;
    float* zbuf = (float*)(lds + LDS_Z_OFF);
    __hip_bfloat16* hbuf = (__hip_bfloat16*)(lds + LDS_H_OFF);

    const int tid = threadIdx.x;
    const int wg = blockIdx.x;
    const int xg = wg >> 5;
    const int slot = wg & 31;
    const int layer = slot >> 4;
    const int ct = slot & 15;
    const int lane = tid & 63;
    const int wv = tid >> 6;
    const int mt = wv & 1;          // M-tile (16 rows)
    const int nt = wv >> 1;         // gate (N-tile of 16)
    const int lrow = lane & 15;
    const int lk8 = (lane >> 4) * 8;
    const int crow = (lane >> 4) * 4;

    const int K = layer ? K1 : K0P;
    const int KS = layer ? KS1 : KS0;

    // preload BOTH phases' weight slices into LDS (no reload at s=256)
    for (int ph = 0; ph < 2; ++ph) {
        const __hip_bfloat16* src = wsb +
            (layer ? (ph ? OFF_W1D : OFF_W1E) : (ph ? OFF_W0D : OFF_W0E)) +
            (size_t)ct * 64 * K;
        __hip_bfloat16* dstW = Wlds + ph * 64 * KS;
        const int KC = K >> 3;
        for (int e = tid; e < 64 * KC; e += 512) {
            int p = e / KC, kc = e - p * KC;
            *(short8*)&dstW[p * KS + kc * 8] =
                *(const short8*)&src[(size_t)p * K + kc * 8];
        }
    }
    const int gb = tid >> 4, gj = tid & 15;   // gate-thread (row, col)
    const int jcol = ct * 16 + gj;
    float br[2][4];
    #pragma unroll
    for (int ph = 0; ph < 2; ++ph)
        #pragma unroll
        for (int g = 0; g < 4; ++g)
            br[ph][g] = bsum[ph * 2048 + layer * 1024 + g * 256 + jcol];
    float creg = 0.f;
    __syncthreads();

    const __hip_bfloat16* Xbf = wsb + OFF_XBF;
    __hip_bfloat16* h0g = h0ring + (size_t)xg * RGELEM;
    __hip_bfloat16* h1g = h1ring + (size_t)xg * RGELEM;
    int* flg = flags + xg * 32;

    const int arow = mt * 16 + lrow;
    short8 xv[5], xvn[5];
    if (layer == 0) {
        const short8* xp = (const short8*)&Xbf[((size_t)0 * BB + xg * ROWS + arow) * XP];
        #pragma unroll
        for (int kt = 0; kt < 5; ++kt) xv[kt] = xp[kt * 4 + (lk8 >> 3)];
    }

    for (int s = 0; s < STEPS; ++s) {
        const int ph = s >> 8;

        // ---- poll peer flags (wave 0; relaxed agent loads, no cache-maint)
        if (wv == 0) {
            int tgt = 0;
            if (lane < 16)      tgt = layer ? (s + 1) : s;       // L0 flags
            else if (lane < 32) tgt = layer ? s : (s - (RING - 1)); // L1 flags
            if (tgt > 0) {
                int* fp = flg + (lane & 31);
                int guard = 0;
                while (__hip_atomic_load(fp, __ATOMIC_RELAXED,
                                         __HIP_MEMORY_SCOPE_AGENT) < tgt) {
                    __builtin_amdgcn_s_sleep(1);
                    if (++guard > (1 << 21)) break;   // bounded: no infinite hang
                }
            }
        }
        __syncthreads();

        // ---- prefetch next-step x (L0), hides HBM latency under this step
        if (layer == 0) {
            int sn = (s + 1 < STEPS) ? s + 1 : s;
            const short8* xp =
                (const short8*)&Xbf[((size_t)sn * BB + xg * ROWS + arow) * XP];
            #pragma unroll
            for (int kt = 0; kt < 5; ++kt) xvn[kt] = xp[kt * 4 + (lk8 >> 3)];
        }

        // ---- GEMM (hoisted ring loads so they pipeline, then MFMA chain)
        f32x4 acc = {0.f, 0.f, 0.f, 0.f};
        if (layer == 0) {
            u64* hp = (u64*)&h0g[(size_t)((s + RING - 1) & (RING - 1)) * (ROWS * HH)
                                 + (size_t)arow * HH];
            u64 rv[16];
            #pragma unroll
            for (int i = 0; i < 8; ++i) {
                rv[2 * i]     = __hip_atomic_load(hp + (i * 32 + lk8) / 4,
                                    __ATOMIC_RELAXED, __HIP_MEMORY_SCOPE_AGENT);
                rv[2 * i + 1] = __hip_atomic_load(hp + (i * 32 + lk8) / 4 + 1,
                                    __ATOMIC_RELAXED, __HIP_MEMORY_SCOPE_AGENT);
            }
            const __hip_bfloat16* Wp = Wlds + ph * 64 * KS0;
            #pragma unroll
            for (int kt = 0; kt < 13; ++kt) {
                short8 a;
                if (kt < 5) a = xv[kt];
                else {
                    union { u64 u[2]; short8 s8; } cv;
                    cv.u[0] = rv[2 * (kt - 5)];
                    cv.u[1] = rv[2 * (kt - 5) + 1];
                    a = cv.s8;
                }
                short8 w = *(const short8*)&Wp[(nt * 16 + lrow) * KS0 + kt * 32 + lk8];
                acc = __builtin_amdgcn_mfma_f32_16x16x32_bf16(a, w, acc, 0, 0, 0);
            }
        } else {
            u64* h0p = (u64*)&h0g[(size_t)(s & (RING - 1)) * (ROWS * HH)
                                  + (size_t)arow * HH];
            u64* h1p = (u64*)&h1g[(size_t)((s + RING - 1) & (RING - 1)) * (ROWS * HH)
                                  + (size_t)arow * HH];
            u64 rv[32];
            #pragma unroll
            for (int i = 0; i < 8; ++i) {
                rv[2 * i]      = __hip_atomic_load(h0p + (i * 32 + lk8) / 4,
                                     __ATOMIC_RELAXED, __HIP_MEMORY_SCOPE_AGENT);
                rv[2 * i + 1]  = __hip_atomic_load(h0p + (i * 32 + lk8) / 4 + 1,
                                     __ATOMIC_RELAXED, __HIP_MEMORY_SCOPE_AGENT);
                rv[16 + 2 * i] = __hip_atomic_load(h1p + (i * 32 + lk8) / 4,
                                     __ATOMIC_RELAXED, __HIP_MEMORY_SCOPE_AGENT);
                rv[17 + 2 * i] = __hip_atomic_load(h1p + (i * 32 + lk8) / 4 + 1,
                                     __ATOMIC_RELAXED, __HIP_MEMORY_SCOPE_AGENT);
            }
            const __hip_bfloat16* Wp = Wlds + ph * 64 * KS1;
            #pragma unroll
            for (int kt = 0; kt < 16; ++kt) {
                union { u64 u[2]; short8 s8; } cv;
                cv.u[0] = rv[2 * kt];
                cv.u[1] = rv[2 * kt + 1];
                short8 w = *(const short8*)&Wp[(nt * 16 + lrow) * KS1 + kt * 32 + lk8];
                acc = __builtin_amdgcn_mfma_f32_16x16x32_bf16(cv.s8, w, acc, 0, 0, 0);
            }
        }
        #pragma unroll
        for (int r = 0; r < 4; ++r)
            zbuf[(mt * 16 + crow + r) * 68 + nt * 16 + lrow] = acc[r];
        __syncthreads();

        // ---- gates: thread owns (gb, jcol); all 4 gates from zbuf
        {
            float zi = zbuf[gb * 68 + 0 + gj] + br[ph][0];
            float zf = zbuf[gb * 68 + 16 + gj] + br[ph][1];
            float zg = zbuf[gb * 68 + 32 + gj] + br[ph][2];
            float zo = zbuf[gb * 68 + 48 + gj] + br[ph][3];
            float ig = fsigm(zi), fg = fsigm(zf), og = fsigm(zo);
            float cn = fg * creg + ig * ftanh(zg);
            creg = cn;
            hbuf[gb * 16 + gj] = __float2bfloat16(og * ftanh(cn));
        }
        __syncthreads();

        // ---- publish h: 8B atomic stores -> IF$, drain, then flag
        if (tid < 128) {
            int b = tid >> 2, q = tid & 3;
            u64 hv = ((const u64*)hbuf)[tid];
            __hip_bfloat16* rb = (layer ? h1g : h0g)
                                 + (size_t)(s & (RING - 1)) * (ROWS * HH);
            __hip_atomic_store((u64*)&rb[b * HH + ct * 16 + q * 4], hv,
                               __ATOMIC_RELAXED, __HIP_MEMORY_SCOPE_AGENT);
            if (layer == 1 && s >= 256)
                *(u64*)&h1all[((size_t)(s - 256) * BB + xg * ROWS + b) * HH
                              + ct * 16 + q * 4] = hv;
            asm volatile("s_waitcnt vmcnt(0)" ::: "memory");
        }
        __syncthreads();
        if (tid == 0)
            __hip_atomic_store(flg + slot, s + 1, __ATOMIC_RELAXED,
                               __HIP_MEMORY_SCOPE_AGENT);

        if (layer == 0) {
            #pragma unroll
            for (int kt = 0; kt < 5; ++kt) xv[kt] = xvn[kt];
        }
    }
}

// ---------------- MFMA emit: logits + log_softmax ----------------
__global__ __launch_bounds__(256) void emit_mfma(
    const __hip_bfloat16* __restrict__ h1all,
    const __hip_bfloat16* __restrict__ lW,
    const float* __restrict__ lb,
    float* __restrict__ out) {
    __shared__ float lbs[160];
    const int tid = threadIdx.x;
    const int wv = tid >> 6, lane = tid & 63;
    const int lrow = lane & 15, lk8 = (lane >> 4) * 8, crow = (lane >> 4) * 4;
    const int row0 = blockIdx.x * 64;
    if (tid < 160) lbs[tid] = lb[tid];
    __syncthreads();

    f32x4 acc[10];
    #pragma unroll
    for (int f = 0; f < 10; ++f) acc[f] = (f32x4){0.f, 0.f, 0.f, 0.f};
    const int arow = row0 + wv * 16 + lrow;
    #pragma unroll
    for (int kt = 0; kt < 8; ++kt) {
        short8 a = *reinterpret_cast<const short8*>(
            &h1all[(size_t)arow * HH + kt * 32 + lk8]);
        #pragma unroll
        for (int f = 0; f < 10; ++f) {
            short8 w = *reinterpret_cast<const short8*>(
                &lW[(size_t)(f * 16 + lrow) * HH + kt * 32 + lk8]);
            acc[f] = __builtin_amdgcn_mfma_f32_16x16x32_bf16(a, w, acc[f], 0, 0, 0);
        }
    }
    #pragma unroll
    for (int r = 0; r < 4; ++r) {
        float m = -3.0e38f;
        #pragma unroll
        for (int f = 0; f < 10; ++f) m = fmaxf(m, acc[f][r] + lbs[f * 16 + lrow]);
        #pragma unroll
        for (int d = 1; d < 16; d <<= 1) m = fmaxf(m, __shfl_xor(m, d, 64));
        float ss = 0.f;
        #pragma unroll
        for (int f = 0; f < 10; ++f) ss += __expf(acc[f][r] + lbs[f * 16 + lrow] - m);
        #pragma unroll
        for (int d = 1; d < 16; d <<= 1) ss += __shfl_xor(ss, d, 64);
        float lse = m + logf(ss);
        int grow = row0 + wv * 16 + crow + r;
        #pragma unroll
        for (int f = 0; f < 9; ++f) {
            int j = f * 16 + lrow;
            if (j < DD)
                out[(size_t)grow * DD + j] = acc[f][r] + lbs[j] - lse;
        }
    }
}

extern "C" void kernel_launch(void* const* d_in, const int* in_sizes, int n_in,
                              void* d_out, int out_size, void* d_ws, size_t ws_size,
                              hipStream_t stream) {
    const float* X     = (const float*)d_in[0];
    const float* Y     = (const float*)d_in[1];
    const float* eWih0 = (const float*)d_in[2];
    const float* eWhh0 = (const float*)d_in[3];
    const float* ebih0 = (const float*)d_in[4];
    const float* ebhh0 = (const float*)d_in[5];
    const float* eWih1 = (const float*)d_in[6];
    const float* eWhh1 = (const float*)d_in[7];
    const float* ebih1 = (const float*)d_in[8];
    const float* ebhh1 = (const float*)d_in[9];
    const float* dWih0 = (const float*)d_in[10];
    const float* dWhh0 = (const float*)d_in[11];
    const float* dbih0 = (const float*)d_in[12];
    const float* dbhh0 = (const float*)d_in[13];
    const float* dWih1 = (const float*)d_in[14];
    const float* dWhh1 = (const float*)d_in[15];
    const float* dbih1 = (const float*)d_in[16];
    const float* dbhh1 = (const float*)d_in[17];
    const float* linW  = (const float*)d_in[18];
    const float* linb  = (const float*)d_in[19];
    float* out = (float*)d_out;

    __hip_bfloat16* wsb = (__hip_bfloat16*)d_ws;
    float* freg  = (float*)(wsb + OFF_BF16_END);
    float* bsum  = freg;                       // 4096 f32
    float* linbp = freg + 4096;                // 192
    int*   flags = (int*)(freg + 4096 + 192);  // 256 ints (128B/group)

    pack_w0<<<dim3(1664), dim3(256), 0, stream>>>(eWih0, eWhh0, wsb + OFF_W0E);
    pack_w0<<<dim3(1664), dim3(256), 0, stream>>>(dWih0, dWhh0, wsb + OFF_W0D);
    pack_w1<<<dim3(2048), dim3(256), 0, stream>>>(eWih1, eWhh1, wsb + OFF_W1E);
    pack_w1<<<dim3(2048), dim3(256), 0, stream>>>(dWih1, dWhh1, wsb + OFF_W1D);
    pack_bias<<<dim3(4), dim3(256), 0, stream>>>(ebih0, ebhh0, bsum + 0);
    pack_bias<<<dim3(4), dim3(256), 0, stream>>>(ebih1, ebhh1, bsum + 1024);
    pack_bias<<<dim3(4), dim3(256), 0, stream>>>(dbih0, dbhh0, bsum + 2048);
    pack_bias<<<dim3(4), dim3(256), 0, stream>>>(dbih1, dbhh1, bsum + 3072);
    pack_xbf<<<dim3(81920), dim3(256), 0, stream>>>(X, Y, wsb + OFF_XBF);
    pack_linw<<<dim3(160), dim3(256), 0, stream>>>(linW, wsb + OFF_LW);
    pack_linb<<<dim3(1), dim3(256), 0, stream>>>(linb, linbp);
    init_sync<<<dim3(512), dim3(256), 0, stream>>>(wsb + OFF_H0R, flags);

    hipFuncSetAttribute((const void*)lstm_persistent,
                        hipFuncAttributeMaxDynamicSharedMemorySize, LDS_TOTAL);
    lstm_persistent<<<dim3(256), dim3(512), LDS_TOTAL, stream>>>(
        wsb, bsum, flags, wsb + OFF_H0R, wsb + OFF_H1R, wsb + OFF_H1A);

    emit_mfma<<<dim3(1024), dim3(256), 0, stream>>>(wsb + OFF_H1A, wsb + OFF_LW,
                                                    linbp, out);
}